// Round 1
// baseline (862.696 us; speedup 1.0000x reference)
//
#include <hip/hip_runtime.h>
#include <hip/hip_bf16.h>
#include <stdint.h>

#define HH 512
#define BB 32
#define SSEQ 256
#define TVOC 50003
#define EPSF 1e-10f

typedef float f32x4 __attribute__((ext_vector_type(4)));

__device__ __forceinline__ float wave_max(float v) {
#pragma unroll
  for (int off = 32; off; off >>= 1) v = fmaxf(v, __shfl_xor(v, off));
  return v;
}
__device__ __forceinline__ float wave_sum(float v) {
#pragma unroll
  for (int off = 32; off; off >>= 1) v += __shfl_xor(v, off);
  return v;
}

// ---------------------------------------------------------------- ws init
__global__ void init_ws_kernel(float* ws) {
  if (threadIdx.x < 8) ws[threadIdx.x] = 0.0f;
}

// ---------------------------------------------------------------- pi softmax
__global__ __launch_bounds__(512) void softmax_pi_kernel(
    const float* __restrict__ x, float* __restrict__ pi) {
  const int tid = threadIdx.x;
  const int wv = tid >> 6, ln = tid & 63;
  __shared__ float red[8];
  float v = x[tid];
  float m = wave_max(v);
  if (ln == 0) red[wv] = m;
  __syncthreads();
  float M = red[0];
#pragma unroll
  for (int i = 1; i < 8; ++i) M = fmaxf(M, red[i]);
  float e = __expf(v - M);
  float s = wave_sum(e);
  __syncthreads();
  if (ln == 0) red[wv] = s;
  __syncthreads();
  float S = 0.f;
#pragma unroll
  for (int i = 0; i < 8; ++i) S += red[i];
  pi[tid] = e / S;
}

// ---------------------------------------------------------------- A softmax + entropy
__global__ __launch_bounds__(512) void softmaxA_kernel(
    const float* __restrict__ tl, float* __restrict__ outA,
    float* __restrict__ ws_ent) {
  const int r = blockIdx.x, tid = threadIdx.x;
  const int wv = tid >> 6, ln = tid & 63;
  __shared__ float red[8];
  float v = tl[(size_t)r * HH + tid];
  float m = wave_max(v);
  if (ln == 0) red[wv] = m;
  __syncthreads();
  float M = red[0];
#pragma unroll
  for (int i = 1; i < 8; ++i) M = fmaxf(M, red[i]);
  float e = __expf(v - M);
  float s = wave_sum(e);
  __syncthreads();
  if (ln == 0) red[wv] = s;
  __syncthreads();
  float S = 0.f;
#pragma unroll
  for (int i = 0; i < 8; ++i) S += red[i];
  float p = e / S;
  outA[(size_t)r * HH + tid] = p;
  float ent = -p * __logf(p + EPSF);
  ent = wave_sum(ent);
  __syncthreads();
  if (ln == 0) red[wv] = ent;
  __syncthreads();
  if (tid == 0) {
    float tot = 0.f;
#pragma unroll
    for (int i = 0; i < 8; ++i) tot += red[i];
    atomicAdd(ws_ent, tot);
  }
}

// ---------------------------------------------------------------- column sums + relu reg
__global__ __launch_bounds__(512) void colsum_kernel(
    const float* __restrict__ outA, const float* __restrict__ thr,
    float* __restrict__ ws_col) {
  const int j = threadIdx.x;
  const int wv = j >> 6, ln = j & 63;
  float s = 0.f;
  for (int i = 0; i < HH; ++i) s += outA[(size_t)i * HH + j];
  float v = fmaxf(thr[0] - s, 0.f);
  v = wave_sum(v);
  __shared__ float red[8];
  if (ln == 0) red[wv] = v;
  __syncthreads();
  if (j == 0) {
    float tot = 0.f;
#pragma unroll
    for (int i = 0; i < 8; ++i) tot += red[i];
    ws_col[0] = tot;  // COLSUM_COEF = 1.0
  }
}

// ---------------------------------------------------------------- B softmax (rows of 50003)
__global__ __launch_bounds__(256) void softmaxB_kernel(
    const float* __restrict__ el, float* __restrict__ outB) {
  const int r = blockIdx.x, tid = threadIdx.x;
  const float* x = el + (size_t)r * TVOC;
  float* yo = outB + (size_t)r * TVOC;
  // rows are only 4B-aligned (50003 odd); peel to 16B for float4 body
  const int mis = (int)(((16u - ((unsigned)(uintptr_t)x & 15u)) & 15u) >> 2);
  const int body = (TVOC - mis) >> 2;
  const int tailoff = mis + body * 4;

  float m = -1e30f, s = 0.f;
  auto upd = [&m, &s](float v) {
    if (v > m) { s = s * __expf(m - v) + 1.f; m = v; }
    else       { s += __expf(v - m); }
  };
  if (tid < mis) upd(x[tid]);
  const float4* x4 = (const float4*)(x + mis);
  for (int i = tid; i < body; i += 256) {
    float4 v = x4[i];
    upd(v.x); upd(v.y); upd(v.z); upd(v.w);
  }
  for (int i = tailoff + tid; i < TVOC; i += 256) upd(x[i]);

  // wave-level (m,s) merge
#pragma unroll
  for (int off = 32; off; off >>= 1) {
    float om = __shfl_down(m, off), os = __shfl_down(s, off);
    float nm = fmaxf(m, om);
    s = s * __expf(m - nm) + os * __expf(om - nm);
    m = nm;
  }
  __shared__ float sm[4], ssv[4];
  __shared__ float bM, biZ;
  if ((tid & 63) == 0) { sm[tid >> 6] = m; ssv[tid >> 6] = s; }
  __syncthreads();
  if (tid == 0) {
    float M = sm[0], S = ssv[0];
#pragma unroll
    for (int w = 1; w < 4; ++w) {
      float nm = fmaxf(M, sm[w]);
      S = S * __expf(M - nm) + ssv[w] * __expf(sm[w] - nm);
      M = nm;
    }
    bM = M; biZ = 1.f / S;
  }
  __syncthreads();
  const float M = bM, iZ = biZ;
  if (tid < mis) yo[tid] = __expf(x[tid] - M) * iZ;
  float4* y4 = (float4*)(yo + mis);
  for (int i = tid; i < body; i += 256) {
    float4 v = x4[i];
    float4 o;
    o.x = __expf(v.x - M) * iZ;
    o.y = __expf(v.y - M) * iZ;
    o.z = __expf(v.z - M) * iZ;
    o.w = __expf(v.w - M) * iZ;
    y4[i] = o;
  }
  for (int i = tailoff + tid; i < TVOC; i += 256)
    yo[i] = __expf(x[i] - M) * iZ;
}

// ---------------------------------------------------------------- gather emissions -> bf16 [S][H][B]
__global__ __launch_bounds__(256) void gather_kernel(
    const int* __restrict__ tok, const float* __restrict__ Bm,
    __hip_bfloat16* __restrict__ ems) {
  const int t = blockIdx.x;
  __shared__ int tk[BB];
  if (threadIdx.x < BB) tk[threadIdx.x] = tok[threadIdx.x * SSEQ + t];
  __syncthreads();
#pragma unroll 1
  for (int idx = threadIdx.x; idx < HH * BB; idx += 256) {
    const int b = idx & 31, j = idx >> 5;
    const float v = Bm[(size_t)j * TVOC + tk[b]] + EPSF;
    ems[((size_t)t * HH + j) * BB + b] = __float2bfloat16(v);
  }
}

// ---------------------------------------------------------------- forward scan
// 2 WGs x 1024 threads. WG h owns batches [h*16, h*16+16). A (x512, fp8 e4m3)
// resident in VGPRs as MFMA A-operand fragments of As^T (M=j tile, K=i).
// Per step: D[j][b] = sum_k AsT_frag x alphaT_frag (alpha fp8 in LDS, dbuf),
// multiply bf16 emissions, max-normalize per batch (track logscale), re-encode.
__global__ __launch_bounds__(1024) void scan_kernel(
    const float* __restrict__ d_pi, const float* __restrict__ d_A,
    const __hip_bfloat16* __restrict__ ems, float* __restrict__ ws_negll) {
  const int h = blockIdx.x;
  const int tid = threadIdx.x;
  const int lane = tid & 63;
  const int wave = tid >> 6;   // 0..15 ; wave owns j-tile [wave*32, wave*32+32)
  const int l15 = lane & 15;
  const int quad = lane >> 4;  // 0..3

  __shared__ __align__(16) unsigned char alpha[2][16][520];  // fp8 [buf][b][state], 8B-aligned rows
  __shared__ float wmax[16][17];
  __shared__ float wsum[16][17];
  __shared__ float ls[16];

  // ---- resident A fragments: A-op layout row=lane&15 (=j), k=quad*8+0..7 (=i)
  long aF[2][16];
#pragma unroll
  for (int n = 0; n < 2; ++n) {
    const int jg = wave * 32 + n * 16 + l15;
#pragma unroll
    for (int kc = 0; kc < 16; ++kc) {
      const int ib = kc * 32 + quad * 8;
      float v[8];
#pragma unroll
      for (int u = 0; u < 8; ++u)
        v[u] = d_A[(size_t)(ib + u) * HH + jg] * 512.0f;  // As = A*512 (EPS negligible vs ~1)
      int lo = 0, hi = 0;
      lo = __builtin_amdgcn_cvt_pk_fp8_f32(v[0], v[1], lo, false);
      lo = __builtin_amdgcn_cvt_pk_fp8_f32(v[2], v[3], lo, true);
      hi = __builtin_amdgcn_cvt_pk_fp8_f32(v[4], v[5], hi, false);
      hi = __builtin_amdgcn_cvt_pk_fp8_f32(v[6], v[7], hi, true);
      aF[n][kc] = (long)(((unsigned long)(unsigned)hi << 32) | (unsigned)lo);
    }
  }

  // ---- t = 0 init: wave w handles local batch b=w (global h*16+w)
  {
    const int b = wave;
    const int j0 = lane * 8;
    float vals[8];
    float m = -1e30f;
#pragma unroll
    for (int u = 0; u < 8; ++u) {
      const float e = __bfloat162float(ems[(size_t)(j0 + u) * BB + h * 16 + b]);
      vals[u] = (d_pi[j0 + u] + EPSF) * e;
      m = fmaxf(m, vals[u]);
    }
    m = wave_max(m);
    if (lane == 0) ls[b] = __logf(m);
    const float r = 1.0f / m;
    int lo = 0, hi = 0;
    lo = __builtin_amdgcn_cvt_pk_fp8_f32(vals[0] * r, vals[1] * r, lo, false);
    lo = __builtin_amdgcn_cvt_pk_fp8_f32(vals[2] * r, vals[3] * r, lo, true);
    hi = __builtin_amdgcn_cvt_pk_fp8_f32(vals[4] * r, vals[5] * r, hi, false);
    hi = __builtin_amdgcn_cvt_pk_fp8_f32(vals[6] * r, vals[7] * r, hi, true);
    *(unsigned int*)&alpha[0][b][j0]     = (unsigned)lo;
    *(unsigned int*)&alpha[0][b][j0 + 4] = (unsigned)hi;
  }
  __syncthreads();

#pragma unroll 1
  for (int t = 1; t < SSEQ; ++t) {
    const int cur = (t - 1) & 1, nxt = t & 1;
    // emission prefetch (independent of MFMA chain -> hidden under it)
    float ev[2][4];
#pragma unroll
    for (int n = 0; n < 2; ++n)
#pragma unroll
      for (int rg = 0; rg < 4; ++rg) {
        const int j = wave * 32 + n * 16 + quad * 4 + rg;
        ev[n][rg] = __bfloat162float(ems[((size_t)t * HH + j) * BB + h * 16 + l15]);
      }

    f32x4 acc0 = {0.f, 0.f, 0.f, 0.f}, acc1 = {0.f, 0.f, 0.f, 0.f};
#pragma unroll
    for (int kc = 0; kc < 16; ++kc) {
      const long bf = *(const long*)&alpha[cur][l15][kc * 32 + quad * 8];
      acc0 = __builtin_amdgcn_mfma_f32_16x16x32_fp8_fp8(aF[0][kc], bf, acc0, 0, 0, 0);
      acc1 = __builtin_amdgcn_mfma_f32_16x16x32_fp8_fp8(aF[1][kc], bf, acc1, 0, 0, 0);
    }

    // D layout: col(b)=lane&15, row(j within subtile)=quad*4+reg
    float y[2][4];
    float mm = -1e30f;
#pragma unroll
    for (int rg = 0; rg < 4; ++rg) {
      y[0][rg] = acc0[rg] * ev[0][rg];
      y[1][rg] = acc1[rg] * ev[1][rg];
      mm = fmaxf(mm, fmaxf(y[0][rg], y[1][rg]));
    }
    mm = fmaxf(mm, __shfl_xor(mm, 16));
    mm = fmaxf(mm, __shfl_xor(mm, 32));
    if (lane < 16) wmax[wave][lane] = mm;
    __syncthreads();
    float m = wmax[0][l15];
#pragma unroll
    for (int w = 1; w < 16; ++w) m = fmaxf(m, wmax[w][l15]);
    const float r = 1.0f / m;
#pragma unroll
    for (int n = 0; n < 2; ++n) {
      int d = 0;
      d = __builtin_amdgcn_cvt_pk_fp8_f32(y[n][0] * r, y[n][1] * r, d, false);
      d = __builtin_amdgcn_cvt_pk_fp8_f32(y[n][2] * r, y[n][3] * r, d, true);
      *(unsigned int*)&alpha[nxt][l15][wave * 32 + n * 16 + quad * 4] = (unsigned)d;
    }
    if (tid < 16) ls[tid] += __logf(m);  // wave0 lanes 0..15: their m is for b=tid
    if (t == SSEQ - 1) {
      float s = (y[0][0] + y[0][1] + y[0][2] + y[0][3] +
                 y[1][0] + y[1][1] + y[1][2] + y[1][3]) * r;
      s += __shfl_xor(s, 16);
      s += __shfl_xor(s, 32);
      if (lane < 16) wsum[wave][lane] = s;
    }
    __syncthreads();
  }

  if (wave == 0 && lane < 16) {
    float s = 0.f;
#pragma unroll
    for (int w = 0; w < 16; ++w) s += wsum[w][lane];
    // LL = log(sum alpha) + logscale - 255*ln(512)   (the x512 As scaling)
    const float LL = __logf(s) + ls[lane] - 1590.7727794f;
    atomicAdd(ws_negll, -LL * (1.0f / 32.0f));
  }
}

// ---------------------------------------------------------------- finalize loss
__global__ void finalize_kernel(const float* __restrict__ ws,
                                float* __restrict__ out_loss) {
  // ws[0]=sum row entropies, ws[1]=-mean LL, ws[2]=colsum reg
  out_loss[0] = ws[1] + ws[0] * (0.1f / 512.0f) + ws[2];
}

// ----------------------------------------------------------------
extern "C" void kernel_launch(void* const* d_in, const int* in_sizes, int n_in,
                              void* d_out, int out_size, void* d_ws, size_t ws_size,
                              hipStream_t stream) {
  const int*   tok    = (const int*)d_in[0];    // [32,256]
  const float* initl  = (const float*)d_in[1];  // [512]
  const float* transl = (const float*)d_in[2];  // [512,512]
  const float* eml    = (const float*)d_in[3];  // [512,50003]
  const float* thr    = (const float*)d_in[4];  // scalar

  float* out      = (float*)d_out;
  float* out_pi   = out;
  float* out_A    = out + HH;
  float* out_B    = out + HH + (size_t)HH * HH;
  float* out_loss = out + HH + (size_t)HH * HH + (size_t)HH * TVOC;

  float* wsf = (float*)d_ws;
  // ems buffer: bf16 [S][H][B] = 8.4 MB at d_ws + 64B
  __hip_bfloat16* ems = (__hip_bfloat16*)((char*)d_ws + 64);

  init_ws_kernel<<<1, 64, 0, stream>>>(wsf);
  softmax_pi_kernel<<<1, 512, 0, stream>>>(initl, out_pi);
  softmaxA_kernel<<<512, 512, 0, stream>>>(transl, out_A, wsf + 0);
  colsum_kernel<<<1, 512, 0, stream>>>(out_A, thr, wsf + 2);
  softmaxB_kernel<<<512, 256, 0, stream>>>(eml, out_B);
  gather_kernel<<<SSEQ, 256, 0, stream>>>(tok, out_B, ems);
  scan_kernel<<<2, 1024, 0, stream>>>(out_pi, out_A, ems, wsf + 1);
  finalize_kernel<<<1, 1, 0, stream>>>(wsf, out_loss);
}

// Round 2
// 598.112 us; speedup vs baseline: 1.4424x; 1.4424x over previous
//
#include <hip/hip_runtime.h>
#include <hip/hip_bf16.h>
#include <stdint.h>

#define HH 512
#define BB 32
#define SSEQ 256
#define TVOC 50003
#define EPSF 1e-10f
#define EMSCALE 96.0f
// 255*ln(512) + 256*ln(96)
#define TOTLOG 2759.2459164008406f

typedef float f32x4 __attribute__((ext_vector_type(4)));
typedef int v8i __attribute__((ext_vector_type(8)));

__device__ __forceinline__ float wave_max(float v) {
#pragma unroll
  for (int off = 32; off; off >>= 1) v = fmaxf(v, __shfl_xor(v, off));
  return v;
}
__device__ __forceinline__ float wave_sum(float v) {
#pragma unroll
  for (int off = 32; off; off >>= 1) v += __shfl_xor(v, off);
  return v;
}

// ---------------------------------------------------------------- ws init
// zeros wsf[0..8) scalars and col[0..512) partial column sums
__global__ __launch_bounds__(512) void init_ws_kernel(float* ws) {
  if (threadIdx.x < 8) ws[threadIdx.x] = 0.0f;
  ws[8 + threadIdx.x] = 0.0f;
}

// ---------------------------------------------------------------- pi softmax
__global__ __launch_bounds__(512) void softmax_pi_kernel(
    const float* __restrict__ x, float* __restrict__ pi) {
  const int tid = threadIdx.x;
  const int wv = tid >> 6, ln = tid & 63;
  __shared__ float red[8];
  float v = x[tid];
  float m = wave_max(v);
  if (ln == 0) red[wv] = m;
  __syncthreads();
  float M = red[0];
#pragma unroll
  for (int i = 1; i < 8; ++i) M = fmaxf(M, red[i]);
  float e = __expf(v - M);
  float s = wave_sum(e);
  __syncthreads();
  if (ln == 0) red[wv] = s;
  __syncthreads();
  float S = 0.f;
#pragma unroll
  for (int i = 0; i < 8; ++i) S += red[i];
  pi[tid] = e / S;
}

// ---------------------------------------------------------------- A softmax + entropy
__global__ __launch_bounds__(512) void softmaxA_kernel(
    const float* __restrict__ tl, float* __restrict__ outA,
    float* __restrict__ ws_ent) {
  const int r = blockIdx.x, tid = threadIdx.x;
  const int wv = tid >> 6, ln = tid & 63;
  __shared__ float red[8];
  float v = tl[(size_t)r * HH + tid];
  float m = wave_max(v);
  if (ln == 0) red[wv] = m;
  __syncthreads();
  float M = red[0];
#pragma unroll
  for (int i = 1; i < 8; ++i) M = fmaxf(M, red[i]);
  float e = __expf(v - M);
  float s = wave_sum(e);
  __syncthreads();
  if (ln == 0) red[wv] = s;
  __syncthreads();
  float S = 0.f;
#pragma unroll
  for (int i = 0; i < 8; ++i) S += red[i];
  float p = e / S;
  outA[(size_t)r * HH + tid] = p;
  float ent = -p * __logf(p + EPSF);
  ent = wave_sum(ent);
  __syncthreads();
  if (ln == 0) red[wv] = ent;
  __syncthreads();
  if (tid == 0) {
    float tot = 0.f;
#pragma unroll
    for (int i = 0; i < 8; ++i) tot += red[i];
    atomicAdd(ws_ent, tot);
  }
}

// ---------------------------------------------------------------- partial column sums (8 blocks x 64 rows)
__global__ __launch_bounds__(512) void colsum_partial_kernel(
    const float* __restrict__ outA, float* __restrict__ col) {
  const int j = threadIdx.x;
  const int i0 = blockIdx.x * 64;
  float s = 0.f;
#pragma unroll 4
  for (int i = i0; i < i0 + 64; ++i) s += outA[(size_t)i * HH + j];
  atomicAdd(&col[j], s);
}

// ---------------------------------------------------------------- B softmax + fused emission gather
// one block per row; writes outB row AND the pre-scaled bf16 emissions
// ems[s][j][b] = softmaxB[r=j][tok[b,s]] * EMSCALE
__global__ __launch_bounds__(1024) void softmaxB_gather_kernel(
    const float* __restrict__ el, float* __restrict__ outB,
    const int* __restrict__ tok, __hip_bfloat16* __restrict__ ems) {
  const int r = blockIdx.x, tid = threadIdx.x;
  const float* x = el + (size_t)r * TVOC;
  float* yo = outB + (size_t)r * TVOC;
  // rows are only 4B-aligned (50003 odd); peel to 16B for float4 body
  const int mis = (int)(((16u - ((unsigned)(uintptr_t)x & 15u)) & 15u) >> 2);
  const int body = (TVOC - mis) >> 2;
  const int tailoff = mis + body * 4;

  float m = -1e30f, s = 0.f;
  auto upd = [&m, &s](float v) {
    if (v > m) { s = s * __expf(m - v) + 1.f; m = v; }
    else       { s += __expf(v - m); }
  };
  if (tid < mis) upd(x[tid]);
  const float4* x4 = (const float4*)(x + mis);
  for (int i = tid; i < body; i += 1024) {
    float4 v = x4[i];
    upd(v.x); upd(v.y); upd(v.z); upd(v.w);
  }
  for (int i = tailoff + tid; i < TVOC; i += 1024) upd(x[i]);

  // wave-level (m,s) merge
#pragma unroll
  for (int off = 32; off; off >>= 1) {
    float om = __shfl_down(m, off), os = __shfl_down(s, off);
    float nm = fmaxf(m, om);
    s = s * __expf(m - nm) + os * __expf(om - nm);
    m = nm;
  }
  __shared__ float sm[16], ssv[16];
  __shared__ float bM, biZ;
  if ((tid & 63) == 0) { sm[tid >> 6] = m; ssv[tid >> 6] = s; }
  __syncthreads();
  if (tid == 0) {
    float M = sm[0], S = ssv[0];
#pragma unroll
    for (int w = 1; w < 16; ++w) {
      float nm = fmaxf(M, sm[w]);
      S = S * __expf(M - nm) + ssv[w] * __expf(sm[w] - nm);
      M = nm;
    }
    bM = M; biZ = 1.f / S;
  }
  __syncthreads();
  const float M = bM, iZ = biZ;
  if (tid < mis) yo[tid] = __expf(x[tid] - M) * iZ;
  float4* y4 = (float4*)(yo + mis);
  for (int i = tid; i < body; i += 1024) {
    float4 v = x4[i];
    float4 o;
    o.x = __expf(v.x - M) * iZ;
    o.y = __expf(v.y - M) * iZ;
    o.z = __expf(v.z - M) * iZ;
    o.w = __expf(v.w - M) * iZ;
    y4[i] = o;
  }
  for (int i = tailoff + tid; i < TVOC; i += 1024)
    yo[i] = __expf(x[i] - M) * iZ;

  // fused gather: 32x256 (b,s) pairs, idx = s*32+b so lanes write contiguous b
  const float gs = EMSCALE * iZ;
  for (int idx = tid; idx < BB * SSEQ; idx += 1024) {
    const int sq = idx >> 5, b = idx & 31;
    const int t = tok[b * SSEQ + sq];
    ems[((size_t)sq * HH + r) * BB + b] = __float2bfloat16(__expf(x[t] - M) * gs);
  }
}

// ---------------------------------------------------------------- forward scan
// 2 WGs x 1024 threads; WG h owns batches [h*16, h*16+16).
// As = A*512 resident in VGPRs as fp8 e4m3 K=128 A-fragments (MX op, trivial
// scales 0x7F). alpha fp8 in LDS, double-buffered, rows padded to 528 B.
// Emissions pre-scaled by EMSCALE so the per-step multiplier ~= 1: no per-step
// normalization needed; renorm (max + log accounting) every 16 steps only.
// Normal step: 1 barrier, 8 MFMA/thread, 8 ds_read_b128/thread.
__global__ __launch_bounds__(1024) void scan_kernel(
    const float* __restrict__ d_pi, const float* __restrict__ d_A,
    const __hip_bfloat16* __restrict__ ems, float* __restrict__ ws_negll) {
  const int h = blockIdx.x;
  const int tid = threadIdx.x;
  const int lane = tid & 63;
  const int wave = tid >> 6;   // 0..15 ; wave owns j-tile [wave*32, wave*32+32)
  const int l15 = lane & 15;
  const int quad = lane >> 4;  // 0..3

  __shared__ __align__(16) unsigned char alpha[2][16][528];  // [buf][b][state(k)]
  __shared__ float wmax[16][17];
  __shared__ float wsum[16][17];
  __shared__ float ls[16];

  const unsigned short* emsu = (const unsigned short*)ems;

  // ---- resident A fragments: k byte p of chunk c <-> k = c*128 + quad*32 + p
  v8i aF[2][4];
#pragma unroll
  for (int n = 0; n < 2; ++n) {
    const int jg = wave * 32 + n * 16 + l15;
#pragma unroll
    for (int c = 0; c < 4; ++c) {
#pragma unroll
      for (int g = 0; g < 8; ++g) {
        const int k0 = c * 128 + quad * 32 + g * 4;
        const float v0 = d_A[(size_t)(k0 + 0) * HH + jg] * 512.0f;
        const float v1 = d_A[(size_t)(k0 + 1) * HH + jg] * 512.0f;
        const float v2 = d_A[(size_t)(k0 + 2) * HH + jg] * 512.0f;
        const float v3 = d_A[(size_t)(k0 + 3) * HH + jg] * 512.0f;
        int wrd = 0;
        wrd = __builtin_amdgcn_cvt_pk_fp8_f32(v0, v1, wrd, false);
        wrd = __builtin_amdgcn_cvt_pk_fp8_f32(v2, v3, wrd, true);
        aF[n][c][g] = wrd;
      }
    }
  }

  // ---- t = 0 init: wave w handles local batch b=w (global h*16+w)
  {
    const int b = wave;
    const int j0 = lane * 8;
    float vals[8];
    float m = -1e30f;
#pragma unroll
    for (int u = 0; u < 8; ++u) {
      const float e = __bfloat162float(ems[(size_t)(j0 + u) * BB + h * 16 + b]);
      vals[u] = (d_pi[j0 + u] + EPSF) * e;
      m = fmaxf(m, vals[u]);
    }
    m = wave_max(m);
    if (lane == 0) ls[b] = __logf(m);
    const float r = 1.0f / m;
    int lo = 0, hi = 0;
    lo = __builtin_amdgcn_cvt_pk_fp8_f32(vals[0] * r, vals[1] * r, lo, false);
    lo = __builtin_amdgcn_cvt_pk_fp8_f32(vals[2] * r, vals[3] * r, lo, true);
    hi = __builtin_amdgcn_cvt_pk_fp8_f32(vals[4] * r, vals[5] * r, hi, false);
    hi = __builtin_amdgcn_cvt_pk_fp8_f32(vals[6] * r, vals[7] * r, hi, true);
    *(unsigned int*)&alpha[0][b][j0]     = (unsigned)lo;
    *(unsigned int*)&alpha[0][b][j0 + 4] = (unsigned)hi;
  }
  __syncthreads();

  // ---- preload emissions for t=1 (raw bf16)
  unsigned short evr[2][4];
#pragma unroll
  for (int n = 0; n < 2; ++n)
#pragma unroll
    for (int rg = 0; rg < 4; ++rg) {
      const int j = wave * 32 + n * 16 + quad * 4 + rg;
      evr[n][rg] = emsu[((size_t)1 * HH + j) * BB + h * 16 + l15];
    }

#pragma unroll 1
  for (int t = 1; t < SSEQ; ++t) {
    const int cur = (t - 1) & 1, nxt = t & 1;

    // this step's emissions (loaded last iteration), then prefetch t+1
    float ev[2][4];
#pragma unroll
    for (int n = 0; n < 2; ++n)
#pragma unroll
      for (int rg = 0; rg < 4; ++rg) {
        const unsigned u = (unsigned)evr[n][rg] << 16;
        ev[n][rg] = __uint_as_float(u);
      }
    const int tp = (t + 1 < SSEQ) ? t + 1 : SSEQ - 1;
#pragma unroll
    for (int n = 0; n < 2; ++n)
#pragma unroll
      for (int rg = 0; rg < 4; ++rg) {
        const int j = wave * 32 + n * 16 + quad * 4 + rg;
        evr[n][rg] = emsu[((size_t)tp * HH + j) * BB + h * 16 + l15];
      }

    f32x4 acc0 = {0.f, 0.f, 0.f, 0.f}, acc1 = {0.f, 0.f, 0.f, 0.f};
#pragma unroll
    for (int c = 0; c < 4; ++c) {
      const unsigned char* ap = &alpha[cur][l15][c * 128 + quad * 32];
      const int4 lo = *(const int4*)ap;
      const int4 hi = *(const int4*)(ap + 16);
      v8i bf;
      bf[0] = lo.x; bf[1] = lo.y; bf[2] = lo.z; bf[3] = lo.w;
      bf[4] = hi.x; bf[5] = hi.y; bf[6] = hi.z; bf[7] = hi.w;
      acc0 = __builtin_amdgcn_mfma_scale_f32_16x16x128_f8f6f4(
          aF[0][c], bf, acc0, 0, 0, 0, 0x7F7F7F7F, 0, 0x7F7F7F7F);
      acc1 = __builtin_amdgcn_mfma_scale_f32_16x16x128_f8f6f4(
          aF[1][c], bf, acc1, 0, 0, 0, 0x7F7F7F7F, 0, 0x7F7F7F7F);
    }

    // D layout: col(b)=lane&15, row(j within subtile)=quad*4+reg
    float y[2][4];
#pragma unroll
    for (int rg = 0; rg < 4; ++rg) {
      y[0][rg] = acc0[rg] * ev[0][rg];
      y[1][rg] = acc1[rg] * ev[1][rg];
    }

    float r = 1.0f;
    if ((t & 15) == 0) {  // renorm step: global max per batch + log accounting
      float mm = -1e30f;
#pragma unroll
      for (int rg = 0; rg < 4; ++rg)
        mm = fmaxf(mm, fmaxf(y[0][rg], y[1][rg]));
      mm = fmaxf(mm, __shfl_xor(mm, 16));
      mm = fmaxf(mm, __shfl_xor(mm, 32));
      if (lane < 16) wmax[wave][lane] = mm;
      __syncthreads();
      float m = wmax[0][l15];
#pragma unroll
      for (int w = 1; w < 16; ++w) m = fmaxf(m, wmax[w][l15]);
      r = 1.0f / m;
      if (tid < 16) ls[tid] += __logf(m);
    }

#pragma unroll
    for (int n = 0; n < 2; ++n) {
      int d = 0;
      d = __builtin_amdgcn_cvt_pk_fp8_f32(y[n][0] * r, y[n][1] * r, d, false);
      d = __builtin_amdgcn_cvt_pk_fp8_f32(y[n][2] * r, y[n][3] * r, d, true);
      *(unsigned int*)&alpha[nxt][l15][wave * 32 + n * 16 + quad * 4] = (unsigned)d;
    }
    if (t == SSEQ - 1) {
      float s = (y[0][0] + y[0][1] + y[0][2] + y[0][3] +
                 y[1][0] + y[1][1] + y[1][2] + y[1][3]) * r;
      s += __shfl_xor(s, 16);
      s += __shfl_xor(s, 32);
      if (lane < 16) wsum[wave][lane] = s;
    }
    __syncthreads();
  }

  if (wave == 0 && lane < 16) {
    float s = 0.f;
#pragma unroll
    for (int w = 0; w < 16; ++w) s += wsum[w][lane];
    // LL = log(sum alpha) + logscale - (255*log512 + 256*logEMSCALE)
    const float LL = __logf(s) + ls[lane] - TOTLOG;
    atomicAdd(ws_negll, -LL * (1.0f / 32.0f));
  }
}

// ---------------------------------------------------------------- finalize loss
__global__ __launch_bounds__(512) void finalize_kernel(
    const float* __restrict__ ws, const float* __restrict__ col,
    const float* __restrict__ thr, float* __restrict__ out_loss) {
  const int j = threadIdx.x;
  float v = fmaxf(thr[0] - col[j], 0.f);
  v = wave_sum(v);
  __shared__ float red[8];
  if ((j & 63) == 0) red[j >> 6] = v;
  __syncthreads();
  if (j == 0) {
    float creg = 0.f;
#pragma unroll
    for (int i = 0; i < 8; ++i) creg += red[i];
    // ws[0]=sum row entropies, ws[1]=-mean LL ; COLSUM_COEF=1.0
    out_loss[0] = ws[1] + ws[0] * (0.1f / 512.0f) + creg;
  }
}

// ----------------------------------------------------------------
extern "C" void kernel_launch(void* const* d_in, const int* in_sizes, int n_in,
                              void* d_out, int out_size, void* d_ws, size_t ws_size,
                              hipStream_t stream) {
  const int*   tok    = (const int*)d_in[0];    // [32,256]
  const float* initl  = (const float*)d_in[1];  // [512]
  const float* transl = (const float*)d_in[2];  // [512,512]
  const float* eml    = (const float*)d_in[3];  // [512,50003]
  const float* thr    = (const float*)d_in[4];  // scalar

  float* out      = (float*)d_out;
  float* out_pi   = out;
  float* out_A    = out + HH;
  float* out_B    = out + HH + (size_t)HH * HH;
  float* out_loss = out + HH + (size_t)HH * HH + (size_t)HH * TVOC;

  float* wsf = (float*)d_ws;           // [0..8) scalars, [8..520) col sums
  float* col = wsf + 8;
  // ems buffer: bf16 [S][H][B] = 8.4 MB
  __hip_bfloat16* ems = (__hip_bfloat16*)((char*)d_ws + 4096);

  init_ws_kernel<<<1, 512, 0, stream>>>(wsf);
  softmax_pi_kernel<<<1, 512, 0, stream>>>(initl, out_pi);
  softmaxA_kernel<<<512, 512, 0, stream>>>(transl, out_A, wsf + 0);
  colsum_partial_kernel<<<8, 512, 0, stream>>>(out_A, col);
  softmaxB_gather_kernel<<<512, 1024, 0, stream>>>(eml, out_B, tok, ems);
  scan_kernel<<<2, 1024, 0, stream>>>(out_pi, out_A, ems, wsf + 1);
  finalize_kernel<<<1, 512, 0, stream>>>(wsf, col, thr, out_loss);
}